// Round 5
// baseline (775.699 us; speedup 1.0000x reference)
//
#include <hip/hip_runtime.h>
#include <hip/hip_cooperative_groups.h>

// SSN superpixel EM, MI355X. B=4, H=W=256, C=20, KG=16 (K=256), CELL=16, 10 EM iters.
// Dataflow single kernel, gather-based M-step (NO data atomics):
//   per iter: gate(dist-1) -> E-step -> post 189 partials (sc1) -> gate(dist-1)
//             -> gather 9 producers' partials for OWN cell -> post Scell (sc1).
// All cross-block data uses agent-scope atomic load/store = coherent-point access.
// Output written with nontemporal float4 (no RFO / L2 churn on the 268MB stream).

#define NBATCH 4
#define WIMG   256
#define NC     20      // feature channels
#define NCS    21      // channels + colsum slot
#define PSTR   24      // padded floats per 21-vec slot
#define NKG    16
#define NK     256
#define NPIX   65536
#define CELLSZ 16
#define LDST   260     // LDS row stride (floats)

typedef float floatx4 __attribute__((ext_vector_type(4)));   // native vector for NT stores

__device__ __forceinline__ float dot4f(const float4 a, const float4 b) {
    return fmaf(a.x, b.x, fmaf(a.y, b.y, fmaf(a.z, b.z, a.w * b.w)));
}

__device__ __forceinline__ float ld_sc1(const float* p) {
    return __hip_atomic_load(p, __ATOMIC_RELAXED, __HIP_MEMORY_SCOPE_AGENT);
}
__device__ __forceinline__ void st_sc1(float* p, float v) {
    __hip_atomic_store(p, v, __ATOMIC_RELAXED, __HIP_MEMORY_SCOPE_AGENT);
}

__device__ __forceinline__ void load_feat(const float* __restrict__ feat, int b, int n, float f[NC]) {
    const float4* fp = (const float4*)(feat + ((size_t)b * NPIX + n) * NC);  // 80B/pixel, 16B aligned
    #pragma unroll
    for (int i = 0; i < 5; ++i) {
        float4 v = fp[i];
        f[4 * i + 0] = v.x; f[4 * i + 1] = v.y; f[4 * i + 2] = v.z; f[4 * i + 3] = v.w;
    }
}

// Wait until the 9 distance-1 neighbor blocks (same batch) reach phase >= target.
__device__ __forceinline__ void gate9(int* done, int target, int b, int cy, int cx, int t) {
    if (t < 9) {
        int ky = cy + t / 3 - 1, kx = cx + t % 3 - 1;
        if (ky >= 0 && ky < NKG && kx >= 0 && kx < NKG) {
            int idx = b * NK + ky * NKG + kx;
            while (__hip_atomic_load(&done[idx], __ATOMIC_RELAXED, __HIP_MEMORY_SCOPE_AGENT) < target) {
                __builtin_amdgcn_s_sleep(2);
            }
        }
    }
    __syncthreads();
}

// E-step vs 9 neighbor cells whose S-vectors are staged in LDS sS[9][PSTR] (slot 20 = colsum).
// rr[j] = 1/col_j, mt[j] = ||mean_j||^2 precomputed. feat_sq cancels in softmax.
__device__ __forceinline__ void e_step_l(const float* f, int cy, int cx,
                                         const float* sS, const float* rrL, const float* mtL,
                                         float p[9]) {
    float a[9];
    float amax = -1e30f;
    #pragma unroll
    for (int dy = -1; dy <= 1; ++dy) {
        #pragma unroll
        for (int dx = -1; dx <= 1; ++dx) {
            int j = (dy + 1) * 3 + (dx + 1);
            int ky = cy + dy, kx = cx + dx;
            if (ky >= 0 && ky < NKG && kx >= 0 && kx < NKG) {   // wave-uniform branch
                const float* sp = sS + j * PSTR;
                float dots = 0.f;
                #pragma unroll
                for (int c = 0; c < NC; ++c) dots = fmaf(f[c], sp[c], dots);
                a[j] = 2.0f * rrL[j] * dots - mtL[j];
                amax = fmaxf(amax, a[j]);
            } else {
                a[j] = -1e30f;
            }
        }
    }
    float esum = 0.f;
    #pragma unroll
    for (int j = 0; j < 9; ++j) {
        float e = (a[j] > -1e29f) ? __expf(a[j] - amax) : 0.0f;
        p[j] = e;
        esum += e;
    }
    float inv = 1.0f / esum;
    #pragma unroll
    for (int j = 0; j < 9; ++j) p[j] *= inv;
}

// Phase protocol (done[blk]): 1 = Scell_0 posted; for it=1..9: 2*it = partials_it posted,
// 2*it+1 = Scell_it posted. Final E-step gates on neighbors >= 19.
__global__ __launch_bounds__(256, 4) void k_ssn_g(const float* __restrict__ feat,
                                                  int* __restrict__ done,
                                                  float* __restrict__ Sc,   // [10][B][K][PSTR]
                                                  float* __restrict__ Pp,   // [10][B][K][9][PSTR]
                                                  float* __restrict__ out) {
    __shared__ float fT[NCS * LDST];     // [c][n], row 20 = ones (colsum)
    __shared__ float pT[9 * LDST];       // [j][n]
    __shared__ float part[21 * 8 * 9];   // [tile][kid][3x3]
    __shared__ float sS[9 * PSTR];       // staged neighbor S-vectors
    __shared__ float rrL[9], mtL[9];

    // XCD-band swizzle: xcd = blk&7 owns 2 cell-rows per batch -> neighbors mostly intra-XCD.
    int blk = blockIdx.x;
    int xcd = blk & 7, q = blk >> 3;
    int b = q >> 5, r = q & 31;
    int cy = (xcd << 1) | (r >> 4), cx = r & 15;
    int k0 = cy * NKG + cx;
    int t = threadIdx.x;
    int ly = t >> 4, lx = t & 15;
    int n = (cy * CELLSZ + ly) * WIMG + cx * CELLSZ + lx;

    float f[NC];
    load_feat(feat, b, n, f);
    #pragma unroll
    for (int c = 0; c < NC; ++c) fT[c * LDST + t] = f[c];
    fT[NC * LDST + t] = 1.0f;
    __syncthreads();

    // --- init: post Scell_0 = own-cell sums (col = 256) ---
    if (t < NCS) {
        float s;
        if (t == NC) {
            s = 256.0f;
        } else {
            s = 0.f;
            const float4* row = (const float4*)&fT[t * LDST];
            #pragma unroll 4
            for (int i = 0; i < 64; ++i) { float4 v = row[i]; s += v.x + v.y + v.z + v.w; }
        }
        st_sc1(&Sc[((size_t)(b * NK + k0)) * PSTR + t], s);
    }
    __syncthreads();   // vmcnt drain before flag post
    if (t == 0) __hip_atomic_fetch_add(&done[b * NK + k0], 1, __ATOMIC_RELAXED, __HIP_MEMORY_SCOPE_AGENT);

    // --- 9 EM iterations ---
    for (int it = 1; it <= 9; ++it) {
        const float* Sp = Sc + ((size_t)(it - 1) * NBATCH + b) * NK * PSTR;
        float* Pit = Pp + ((size_t)it * NBATCH + b) * NK * 9 * PSTR;
        float* Snx = Sc + ((size_t)it * NBATCH + b) * NK * PSTR;

        gate9(done, 2 * it - 1, b, cy, cx, t);   // neighbors' Scell_{it-1} visible

        // stage 9 neighbor S-vectors into LDS (coalesced: 21 consecutive lanes per j)
        if (t < 189) {
            int j = t / 21, c = t % 21;
            int ky = cy + j / 3 - 1, kx = cx + j % 3 - 1;
            if (ky >= 0 && ky < NKG && kx >= 0 && kx < NKG)
                sS[j * PSTR + c] = ld_sc1(&Sp[(size_t)(ky * NKG + kx) * PSTR + c]);
        }
        __syncthreads();
        if (t < 9) {  // r_j and ||mean_j||^2
            int ky = cy + t / 3 - 1, kx = cx + t % 3 - 1;
            if (ky >= 0 && ky < NKG && kx >= 0 && kx < NKG) {
                const float* sp = &sS[t * PSTR];
                float ssq = 0.f;
                #pragma unroll
                for (int c = 0; c < NC; ++c) ssq = fmaf(sp[c], sp[c], ssq);
                float rr = 1.0f / fmaxf(sp[NC], 1e-12f);
                rrL[t] = rr;
                mtL[t] = ssq * rr * rr;
            } else { rrL[t] = 1.0f; mtL[t] = 0.0f; }
        }
        __syncthreads();

        float p[9];
        e_step_l(f, cy, cx, sS, rrL, mtL, p);
        #pragma unroll
        for (int j = 0; j < 9; ++j) pT[j * LDST + t] = p[j];
        __syncthreads();

        // Tiled [9x256]x[256x21] reduction: 21 (3j x 3c) tiles x 8 K-splits = 168 threads.
        if (t < 168) {
            int tile = t >> 3, kid = t & 7;
            int j0 = (tile / 7) * 3, c0 = (tile % 7) * 3;
            float acc[3][3] = {};
            #pragma unroll
            for (int ch = 0; ch < 8; ++ch) {
                int nb = kid * 32 + (((ch + kid) & 7) << 2);  // XOR-swizzle breaks bank aliasing
                float4 pv[3], fv[3];
                #pragma unroll
                for (int jj = 0; jj < 3; ++jj) pv[jj] = *(const float4*)&pT[(j0 + jj) * LDST + nb];
                #pragma unroll
                for (int cc = 0; cc < 3; ++cc) fv[cc] = *(const float4*)&fT[(c0 + cc) * LDST + nb];
                #pragma unroll
                for (int jj = 0; jj < 3; ++jj)
                    #pragma unroll
                    for (int cc = 0; cc < 3; ++cc)
                        acc[jj][cc] += dot4f(pv[jj], fv[cc]);
            }
            #pragma unroll
            for (int jj = 0; jj < 3; ++jj)
                #pragma unroll
                for (int cc = 0; cc < 3; ++cc)
                    part[tile * 72 + kid * 9 + jj * 3 + cc] = acc[jj][cc];
        }
        __syncthreads();
        // post own 189 partials (entry j = offset from ME to target cell)
        if (t < 189) {
            int j = t / 21, c = t % 21;
            int tile = (j / 3) * 7 + (c / 3);
            int elem = (j % 3) * 3 + (c % 3);
            float s = 0.f;
            #pragma unroll
            for (int kid = 0; kid < 8; ++kid) s += part[tile * 72 + kid * 9 + elem];
            int ky = cy + j / 3 - 1, kx = cx + j % 3 - 1;
            if (ky >= 0 && ky < NKG && kx >= 0 && kx < NKG)
                st_sc1(&Pit[((size_t)k0 * 9 + j) * PSTR + c], s);
        }
        __syncthreads();
        if (t == 0) __hip_atomic_fetch_add(&done[b * NK + k0], 1, __ATOMIC_RELAXED, __HIP_MEMORY_SCOPE_AGENT);

        gate9(done, 2 * it, b, cy, cx, t);       // producers' partials_it visible

        // gather: Scell_it[k0] = sum over 9 producers of their entry aimed at me
        if (t < NCS) {
            float s = 0.f;
            #pragma unroll
            for (int u = -1; u <= 1; ++u) {
                #pragma unroll
                for (int v = -1; v <= 1; ++v) {
                    int py = cy + u, px = cx + v;
                    if (py >= 0 && py < NKG && px >= 0 && px < NKG) {
                        int e = (1 - u) * 3 + (1 - v);   // entry in producer aimed at me
                        s += ld_sc1(&Pit[((size_t)(py * NKG + px) * 9 + e) * PSTR + t]);
                    }
                }
            }
            st_sc1(&Snx[(size_t)k0 * PSTR + t], s);
        }
        __syncthreads();
        if (t == 0) __hip_atomic_fetch_add(&done[b * NK + k0], 1, __ATOMIC_RELAXED, __HIP_MEMORY_SCOPE_AGENT);
    }

    // --- final E-step + dense [B,N,K] write (zeros included), nontemporal float4 rows ---
    {
        const float* Sp = Sc + ((size_t)9 * NBATCH + b) * NK * PSTR;
        gate9(done, 19, b, cy, cx, t);
        if (t < 189) {
            int j = t / 21, c = t % 21;
            int ky = cy + j / 3 - 1, kx = cx + j % 3 - 1;
            if (ky >= 0 && ky < NKG && kx >= 0 && kx < NKG)
                sS[j * PSTR + c] = ld_sc1(&Sp[(size_t)(ky * NKG + kx) * PSTR + c]);
        }
        __syncthreads();
        if (t < 9) {
            int ky = cy + t / 3 - 1, kx = cx + t % 3 - 1;
            if (ky >= 0 && ky < NKG && kx >= 0 && kx < NKG) {
                const float* sp = &sS[t * PSTR];
                float ssq = 0.f;
                #pragma unroll
                for (int c = 0; c < NC; ++c) ssq = fmaf(sp[c], sp[c], ssq);
                float rr = 1.0f / fmaxf(sp[NC], 1e-12f);
                rrL[t] = rr;
                mtL[t] = ssq * rr * rr;
            } else { rrL[t] = 1.0f; mtL[t] = 0.0f; }
        }
        __syncthreads();

        float p[9];
        e_step_l(f, cy, cx, sS, rrL, mtL, p);
        #pragma unroll
        for (int j = 0; j < 9; ++j) pT[j * LDST + t] = p[j];
        __syncthreads();

        int wv = t >> 6, ln = t & 63;
        int j4[4];
        #pragma unroll
        for (int q2 = 0; q2 < 4; ++q2) {
            int k = 4 * ln + q2;
            int ky = k >> 4, kx = k & 15;
            int dy = ky - cy, dx = kx - cx;
            j4[q2] = (dy >= -1 && dy <= 1 && dx >= -1 && dx <= 1) ? (dy + 1) * 3 + (dx + 1) : -1;
        }
        for (int i = 0; i < 64; ++i) {
            int pix = wv * 64 + i;
            int py = pix >> 4, px = pix & 15;
            int np = (cy * CELLSZ + py) * WIMG + cx * CELLSZ + px;
            floatx4 o;
            o.x = (j4[0] >= 0) ? pT[j4[0] * LDST + pix] : 0.0f;
            o.y = (j4[1] >= 0) ? pT[j4[1] * LDST + pix] : 0.0f;
            o.z = (j4[2] >= 0) ? pT[j4[2] * LDST + pix] : 0.0f;
            o.w = (j4[3] >= 0) ? pT[j4[3] * LDST + pix] : 0.0f;
            size_t rowoff = ((size_t)(b * NPIX + np)) * (size_t)NK;
            __builtin_nontemporal_store(o, (floatx4*)(out + rowoff + 4 * ln));
        }
    }
}

// ---------------- fallback path (proven round-1 kernels, 21-stride layout) ----------------
__device__ __forceinline__ void e_step_fb(const float* f, int b, int cy, int cx,
                                          const float* __restrict__ Sprev, float p[9]) {
    float a[9];
    float amax = -1e30f;
    #pragma unroll
    for (int dy = -1; dy <= 1; ++dy) {
        #pragma unroll
        for (int dx = -1; dx <= 1; ++dx) {
            int j = (dy + 1) * 3 + (dx + 1);
            int ky = cy + dy, kx = cx + dx;
            if (ky >= 0 && ky < NKG && kx >= 0 && kx < NKG) {
                const float* sp = Sprev + ((size_t)(b * NK + ky * NKG + kx)) * NCS;
                float dots = 0.f, ssq = 0.f;
                #pragma unroll
                for (int c = 0; c < NC; ++c) {
                    float sv = sp[c];
                    dots = fmaf(f[c], sv, dots);
                    ssq  = fmaf(sv, sv, ssq);
                }
                float col = fmaxf(sp[NC], 1e-12f);
                float rr = 1.0f / col;
                a[j] = 2.0f * rr * dots - (rr * rr) * ssq;
                amax = fmaxf(amax, a[j]);
            } else {
                a[j] = -1e30f;
            }
        }
    }
    float esum = 0.f;
    #pragma unroll
    for (int j = 0; j < 9; ++j) {
        float e = (a[j] > -1e29f) ? __expf(a[j] - amax) : 0.0f;
        p[j] = e;
        esum += e;
    }
    float inv = 1.0f / esum;
    #pragma unroll
    for (int j = 0; j < 9; ++j) p[j] *= inv;
}

__global__ __launch_bounds__(256, 4) void k_init(const float* __restrict__ feat,
                                                 float* __restrict__ S0,
                                                 float* __restrict__ S1) {
    __shared__ float fT[NC * LDST];
    int blk = blockIdx.x;
    int b = blk >> 8, k0 = blk & 255;
    int cy = k0 >> 4, cx = k0 & 15;
    int t = threadIdx.x;
    int ly = t >> 4, lx = t & 15;
    int n = (cy * CELLSZ + ly) * WIMG + cx * CELLSZ + lx;
    float f[NC];
    load_feat(feat, b, n, f);
    #pragma unroll
    for (int c = 0; c < NC; ++c) fT[c * LDST + t] = f[c];
    __syncthreads();
    if (t < NCS) {
        float s;
        if (t == NC) {
            s = 256.0f;
        } else {
            s = 0.f;
            const float4* row = (const float4*)&fT[t * LDST];
            #pragma unroll 4
            for (int i = 0; i < 64; ++i) { float4 v = row[i]; s += v.x + v.y + v.z + v.w; }
        }
        size_t off = ((size_t)(b * NK + k0)) * NCS + t;
        S0[off] = s;
        S1[off] = 0.0f;
    }
}

__global__ __launch_bounds__(256, 4) void k_em(const float* __restrict__ feat,
                                               const float* __restrict__ Sprev,
                                               float* __restrict__ Snext,
                                               float* __restrict__ Szero) {
    __shared__ float fT[NCS * LDST];
    __shared__ float pT[9 * LDST];
    __shared__ float part[21 * 8 * 9];
    int blk = blockIdx.x;
    int b = blk >> 8, k0 = blk & 255;
    int cy = k0 >> 4, cx = k0 & 15;
    int t = threadIdx.x;
    int ly = t >> 4, lx = t & 15;
    int n = (cy * CELLSZ + ly) * WIMG + cx * CELLSZ + lx;
    float f[NC];
    load_feat(feat, b, n, f);
    #pragma unroll
    for (int c = 0; c < NC; ++c) fT[c * LDST + t] = f[c];
    fT[NC * LDST + t] = 1.0f;
    float p[9];
    e_step_fb(f, b, cy, cx, Sprev, p);
    #pragma unroll
    for (int j = 0; j < 9; ++j) pT[j * LDST + t] = p[j];
    __syncthreads();
    if (t < 168) {
        int tile = t >> 3, kid = t & 7;
        int j0 = (tile / 7) * 3, c0 = (tile % 7) * 3;
        float acc[3][3] = {};
        #pragma unroll
        for (int ch = 0; ch < 8; ++ch) {
            int nb = kid * 32 + (((ch + kid) & 7) << 2);
            float4 pv[3], fv[3];
            #pragma unroll
            for (int jj = 0; jj < 3; ++jj) pv[jj] = *(const float4*)&pT[(j0 + jj) * LDST + nb];
            #pragma unroll
            for (int cc = 0; cc < 3; ++cc) fv[cc] = *(const float4*)&fT[(c0 + cc) * LDST + nb];
            #pragma unroll
            for (int jj = 0; jj < 3; ++jj)
                #pragma unroll
                for (int cc = 0; cc < 3; ++cc)
                    acc[jj][cc] += dot4f(pv[jj], fv[cc]);
        }
        #pragma unroll
        for (int jj = 0; jj < 3; ++jj)
            #pragma unroll
            for (int cc = 0; cc < 3; ++cc)
                part[tile * 72 + kid * 9 + jj * 3 + cc] = acc[jj][cc];
    }
    __syncthreads();
    if (t < 189) {
        int j = t / 21, c = t % 21;
        int tile = (j / 3) * 7 + (c / 3);
        int elem = (j % 3) * 3 + (c % 3);
        float s = 0.f;
        #pragma unroll
        for (int kid = 0; kid < 8; ++kid) s += part[tile * 72 + kid * 9 + elem];
        int ky = cy + (j / 3) - 1, kx = cx + (j % 3) - 1;
        if (ky >= 0 && ky < NKG && kx >= 0 && kx < NKG)
            atomicAdd(&Snext[((size_t)(b * NK + ky * NKG + kx)) * NCS + c], s);
    }
    if (t < NCS) Szero[((size_t)(b * NK + k0)) * NCS + t] = 0.0f;
}

__global__ __launch_bounds__(256, 4) void k_final(const float* __restrict__ feat,
                                                  const float* __restrict__ Sprev,
                                                  float* __restrict__ out) {
    __shared__ float pT[9 * LDST];
    int blk = blockIdx.x;
    int b = blk >> 8, k0 = blk & 255;
    int cy = k0 >> 4, cx = k0 & 15;
    int t = threadIdx.x;
    int ly = t >> 4, lx = t & 15;
    int n = (cy * CELLSZ + ly) * WIMG + cx * CELLSZ + lx;
    float f[NC];
    load_feat(feat, b, n, f);
    float p[9];
    e_step_fb(f, b, cy, cx, Sprev, p);
    #pragma unroll
    for (int j = 0; j < 9; ++j) pT[j * LDST + t] = p[j];
    __syncthreads();
    int wv = t >> 6, ln = t & 63;
    int j4[4];
    #pragma unroll
    for (int q = 0; q < 4; ++q) {
        int k = 4 * ln + q;
        int ky = k >> 4, kx = k & 15;
        int dy = ky - cy, dx = kx - cx;
        j4[q] = (dy >= -1 && dy <= 1 && dx >= -1 && dx <= 1) ? (dy + 1) * 3 + (dx + 1) : -1;
    }
    for (int i = 0; i < 64; ++i) {
        int pix = wv * 64 + i;
        int py = pix >> 4, px = pix & 15;
        int np = (cy * CELLSZ + py) * WIMG + cx * CELLSZ + px;
        float4 o;
        o.x = (j4[0] >= 0) ? pT[j4[0] * LDST + pix] : 0.0f;
        o.y = (j4[1] >= 0) ? pT[j4[1] * LDST + pix] : 0.0f;
        o.z = (j4[2] >= 0) ? pT[j4[2] * LDST + pix] : 0.0f;
        o.w = (j4[3] >= 0) ? pT[j4[3] * LDST + pix] : 0.0f;
        size_t rowoff = ((size_t)(b * NPIX + np)) * (size_t)NK;
        *(float4*)(out + rowoff + 4 * ln) = o;
    }
}

extern "C" void kernel_launch(void* const* d_in, const int* in_sizes, int n_in,
                              void* d_out, int out_size, void* d_ws, size_t ws_size,
                              hipStream_t stream) {
    (void)in_sizes; (void)n_in; (void)out_size;
    const float* feat = (const float*)d_in[0];
    float* out = (float*)d_out;

    // ws layout: int done[1024] @0; Sc float[10][4][256][24] @4096; Pp float[10][4][256][9][24] after.
    int* done = (int*)d_ws;
    float* Sc = (float*)((char*)d_ws + 4096);
    const size_t SC_FLOATS = (size_t)10 * NBATCH * NK * PSTR;           // 245760
    float* Pp = Sc + SC_FLOATS;
    const size_t PP_FLOATS = (size_t)10 * NBATCH * NK * 9 * PSTR;       // 2211840
    const size_t zneed = 4096 + (SC_FLOATS + PP_FLOATS) * sizeof(float);

    dim3 grid(NBATCH * NK), block(256);
    if (ws_size >= zneed) {
        (void)hipMemsetAsync(d_ws, 0, 4096, stream);   // only done[] needs zeroing
        void* args[] = { (void*)&feat, (void*)&done, (void*)&Sc, (void*)&Pp, (void*)&out };
        hipError_t err = hipLaunchCooperativeKernel((const void*)k_ssn_g, grid, block, args, 0, stream);
        if (err == hipSuccess) return;
    }

    // Fallback: serial 11-kernel chain (round-1 proven path).
    const size_t SB = (size_t)NBATCH * NK * NCS;
    float* s0 = (float*)d_ws;
    float* s1 = (float*)d_ws + SB;
    float* s2 = (float*)d_ws + 2 * SB;
    float* bufs[3] = { s0, s1, s2 };
    k_init<<<grid, block, 0, stream>>>(feat, bufs[0], bufs[1]);
    for (int i = 1; i <= 9; ++i)
        k_em<<<grid, block, 0, stream>>>(feat, bufs[(i - 1) % 3], bufs[i % 3], bufs[(i + 1) % 3]);
    k_final<<<grid, block, 0, stream>>>(feat, bufs[0], out);
}

// Round 6
// 715.214 us; speedup vs baseline: 1.0846x; 1.0846x over previous
//
#include <hip/hip_runtime.h>
#include <hip/hip_cooperative_groups.h>

// SSN superpixel EM, MI355X. B=4, H=W=256, C=20, KG=16 (K=256), CELL=16, 10 EM iters.
// Two dispatches:
//  k_em9 (cooperative): init + 9 EM iters, dataflow gates + CONSUMER-side gather of
//    neighbor means from producers' partials (1 gate/iter, no atomics, ping-pong bufs).
//    Writes final means Sc9.
//  k_w (plain): final E-step + dense [B,N,K] output write (268 MB stream, no gates).

#define NBATCH 4
#define WIMG   256
#define NC     20      // feature channels
#define NCS    21      // channels + colsum slot
#define PSTR   24      // padded floats per 21-vec slot
#define NKG    16
#define NK     256
#define NPIX   65536
#define CELLSZ 16
#define LDST   260     // LDS row stride (floats)

typedef float floatx4 __attribute__((ext_vector_type(4)));

__device__ __forceinline__ float dot4f(const float4 a, const float4 b) {
    return fmaf(a.x, b.x, fmaf(a.y, b.y, fmaf(a.z, b.z, a.w * b.w)));
}

__device__ __forceinline__ float ld_ag(const float* p) {
    return __hip_atomic_load(p, __ATOMIC_RELAXED, __HIP_MEMORY_SCOPE_AGENT);
}
__device__ __forceinline__ void st_ag(float* p, float v) {
    __hip_atomic_store(p, v, __ATOMIC_RELAXED, __HIP_MEMORY_SCOPE_AGENT);
}

__device__ __forceinline__ void load_feat(const float* __restrict__ feat, int b, int n, float f[NC]) {
    const float4* fp = (const float4*)(feat + ((size_t)b * NPIX + n) * NC);  // 80B/pixel, 16B aligned
    #pragma unroll
    for (int i = 0; i < 5; ++i) {
        float4 v = fp[i];
        f[4 * i + 0] = v.x; f[4 * i + 1] = v.y; f[4 * i + 2] = v.z; f[4 * i + 3] = v.w;
    }
}

// Wait until blocks within Chebyshev distance rad (same batch) reach phase >= target.
template<int RAD>
__device__ __forceinline__ void gate(int* done, int target, int b, int cy, int cx, int t) {
    constexpr int W = 2 * RAD + 1;
    if (t < W * W) {
        int ky = cy + t / W - RAD, kx = cx + t % W - RAD;
        if (ky >= 0 && ky < NKG && kx >= 0 && kx < NKG) {
            int idx = b * NK + ky * NKG + kx;
            while (__hip_atomic_load(&done[idx], __ATOMIC_RELAXED, __HIP_MEMORY_SCOPE_AGENT) < target) {
                __builtin_amdgcn_s_sleep(4);
            }
        }
    }
    __syncthreads();
}

// E-step vs 9 neighbor cells staged in LDS sS[9][PSTR] (slot 20 = colsum).
// rr[j]=1/col_j, mt[j]=||mean_j||^2. feat_sq cancels in softmax.
__device__ __forceinline__ void e_step_l(const float* f, int cy, int cx,
                                         const float* sS, const float* rrL, const float* mtL,
                                         float p[9]) {
    float a[9];
    float amax = -1e30f;
    #pragma unroll
    for (int dy = -1; dy <= 1; ++dy) {
        #pragma unroll
        for (int dx = -1; dx <= 1; ++dx) {
            int j = (dy + 1) * 3 + (dx + 1);
            int ky = cy + dy, kx = cx + dx;
            if (ky >= 0 && ky < NKG && kx >= 0 && kx < NKG) {   // wave-uniform branch
                const float* sp = sS + j * PSTR;
                float dots = 0.f;
                #pragma unroll
                for (int c = 0; c < NC; ++c) dots = fmaf(f[c], sp[c], dots);
                a[j] = 2.0f * rrL[j] * dots - mtL[j];
                amax = fmaxf(amax, a[j]);
            } else {
                a[j] = -1e30f;
            }
        }
    }
    float esum = 0.f;
    #pragma unroll
    for (int j = 0; j < 9; ++j) {
        float e = (a[j] > -1e29f) ? __expf(a[j] - amax) : 0.0f;
        p[j] = e;
        esum += e;
    }
    float inv = 1.0f / esum;
    #pragma unroll
    for (int j = 0; j < 9; ++j) p[j] *= inv;
}

// rr/mt from staged sS (9 threads).
__device__ __forceinline__ void calc_rrmt(const float* sS, float* rrL, float* mtL,
                                          int cy, int cx, int t) {
    if (t < 9) {
        int ky = cy + t / 3 - 1, kx = cx + t % 3 - 1;
        if (ky >= 0 && ky < NKG && kx >= 0 && kx < NKG) {
            const float* sp = &sS[t * PSTR];
            float ssq = 0.f;
            #pragma unroll
            for (int c = 0; c < NC; ++c) ssq = fmaf(sp[c], sp[c], ssq);
            float rr = 1.0f / fmaxf(sp[NC], 1e-12f);
            rrL[t] = rr;
            mtL[t] = ssq * rr * rr;
        } else { rrL[t] = 1.0f; mtL[t] = 0.0f; }
    }
}

// Flag protocol (done[cell]): 1 = Sc0 posted; it+1 = partials_it posted (it=1..9).
// E-step it=1 gates dist-1 >= 1 (Sc0); it>=2 gates dist-2 >= it (partials_{it-1}).
// Partials ping-pong: partials_it lives in Pbuf[it&1]; gate ordering makes reuse race-free.
__global__ __launch_bounds__(256, 4) void k_em9(const float* __restrict__ feat,
                                                int* __restrict__ done,
                                                float* __restrict__ Sc0,  // [B][K][PSTR]
                                                float* __restrict__ Sc9,  // [B][K][PSTR]
                                                float* __restrict__ Pp0,  // [B][K][9][PSTR]
                                                float* __restrict__ Pp1,  // [B][K][9][PSTR]
                                                float* __restrict__ outdummy) {
    __shared__ float fT[NCS * LDST];     // [c][n], row 20 = ones (colsum)
    __shared__ float pT[9 * LDST];       // [j][n]
    __shared__ float part[21 * 8 * 9];   // [tile][kid][3x3]
    __shared__ float sS[9 * PSTR];       // staged neighbor S-vectors
    __shared__ float rrL[9], mtL[9];
    (void)outdummy;

    // XCD-band swizzle: xcd = blk&7 owns 2 cell-rows per batch -> neighbors mostly intra-XCD.
    int blk = blockIdx.x;
    int xcd = blk & 7, q = blk >> 3;
    int b = q >> 5, r = q & 31;
    int cy = (xcd << 1) | (r >> 4), cx = r & 15;
    int k0 = cy * NKG + cx;
    int t = threadIdx.x;
    int ly = t >> 4, lx = t & 15;
    int n = (cy * CELLSZ + ly) * WIMG + cx * CELLSZ + lx;

    float f[NC];
    load_feat(feat, b, n, f);
    #pragma unroll
    for (int c = 0; c < NC; ++c) fT[c * LDST + t] = f[c];
    fT[NC * LDST + t] = 1.0f;
    __syncthreads();

    // --- init: post Sc0 = own-cell sums (col = 256) ---
    if (t < NCS) {
        float s;
        if (t == NC) {
            s = 256.0f;
        } else {
            s = 0.f;
            const float4* row = (const float4*)&fT[t * LDST];
            #pragma unroll 4
            for (int i = 0; i < 64; ++i) { float4 v = row[i]; s += v.x + v.y + v.z + v.w; }
        }
        st_ag(&Sc0[((size_t)(b * NK + k0)) * PSTR + t], s);
    }
    __syncthreads();   // vmcnt drain before flag post
    if (t == 0) __hip_atomic_fetch_add(&done[b * NK + k0], 1, __ATOMIC_RELAXED, __HIP_MEMORY_SCOPE_AGENT);

    // --- 9 EM iterations, one gate each ---
    for (int it = 1; it <= 9; ++it) {
        float* Pcur = (it & 1) ? Pp1 : Pp0;          // partials_it go here
        const float* Pprv = (it & 1) ? Pp0 : Pp1;    // partials_{it-1} read from here

        if (it == 1) {
            gate<1>(done, 1, b, cy, cx, t);
            // stage neighbors' Sc0 directly
            if (t < 189) {
                int j = t / 21, c = t % 21;
                int ky = cy + j / 3 - 1, kx = cx + j % 3 - 1;
                if (ky >= 0 && ky < NKG && kx >= 0 && kx < NKG)
                    sS[j * PSTR + c] = ld_ag(&Sc0[((size_t)(b * NK + ky * NKG + kx)) * PSTR + c]);
            }
        } else {
            gate<2>(done, it, b, cy, cx, t);
            // consumer gather: Scell_{it-1}[kj] = sum over kj's 9 producers p of
            // Pprv[p][dir(p->kj)]. p within dist-2 of me -> covered by the gate.
            if (t < 189) {
                int j = t / 21, c = t % 21;
                int ky = cy + j / 3 - 1, kx = cx + j % 3 - 1;
                if (ky >= 0 && ky < NKG && kx >= 0 && kx < NKG) {
                    float s = 0.f;
                    #pragma unroll
                    for (int u = -1; u <= 1; ++u) {
                        #pragma unroll
                        for (int v = -1; v <= 1; ++v) {
                            int py = ky + u, px = kx + v;
                            if (py >= 0 && py < NKG && px >= 0 && px < NKG) {
                                int e = (1 - u) * 3 + (1 - v);   // producer's entry aimed at kj
                                s += ld_ag(&Pprv[(((size_t)(b * NK + py * NKG + px)) * 9 + e) * PSTR + c]);
                            }
                        }
                    }
                    sS[j * PSTR + c] = s;
                }
            }
        }
        __syncthreads();
        calc_rrmt(sS, rrL, mtL, cy, cx, t);
        __syncthreads();

        float p[9];
        e_step_l(f, cy, cx, sS, rrL, mtL, p);
        #pragma unroll
        for (int j = 0; j < 9; ++j) pT[j * LDST + t] = p[j];
        __syncthreads();

        // Tiled [9x256]x[256x21] reduction: 21 (3j x 3c) tiles x 8 K-splits = 168 threads.
        if (t < 168) {
            int tile = t >> 3, kid = t & 7;
            int j0 = (tile / 7) * 3, c0 = (tile % 7) * 3;
            float acc[3][3] = {};
            #pragma unroll
            for (int ch = 0; ch < 8; ++ch) {
                int nb = kid * 32 + (((ch + kid) & 7) << 2);  // XOR-swizzle breaks bank aliasing
                float4 pv[3], fv[3];
                #pragma unroll
                for (int jj = 0; jj < 3; ++jj) pv[jj] = *(const float4*)&pT[(j0 + jj) * LDST + nb];
                #pragma unroll
                for (int cc = 0; cc < 3; ++cc) fv[cc] = *(const float4*)&fT[(c0 + cc) * LDST + nb];
                #pragma unroll
                for (int jj = 0; jj < 3; ++jj)
                    #pragma unroll
                    for (int cc = 0; cc < 3; ++cc)
                        acc[jj][cc] += dot4f(pv[jj], fv[cc]);
            }
            #pragma unroll
            for (int jj = 0; jj < 3; ++jj)
                #pragma unroll
                for (int cc = 0; cc < 3; ++cc)
                    part[tile * 72 + kid * 9 + jj * 3 + cc] = acc[jj][cc];
        }
        __syncthreads();
        // post own 189 partials (entry j = offset from ME toward target cell)
        if (t < 189) {
            int j = t / 21, c = t % 21;
            int tile = (j / 3) * 7 + (c / 3);
            int elem = (j % 3) * 3 + (c % 3);
            float s = 0.f;
            #pragma unroll
            for (int kid = 0; kid < 8; ++kid) s += part[tile * 72 + kid * 9 + elem];
            int ky = cy + j / 3 - 1, kx = cx + j % 3 - 1;
            if (ky >= 0 && ky < NKG && kx >= 0 && kx < NKG)
                st_ag(&Pcur[(((size_t)(b * NK + k0)) * 9 + j) * PSTR + c], s);
        }
        __syncthreads();   // vmcnt drain
        if (t == 0) __hip_atomic_fetch_add(&done[b * NK + k0], 1, __ATOMIC_RELAXED, __HIP_MEMORY_SCOPE_AGENT);
    }

    // --- final: gather OWN Scell_9 (producers = my dist-1 neighbors), store for k_w ---
    gate<1>(done, 10, b, cy, cx, t);
    if (t < NCS) {
        const float* P9 = Pp1;   // 9 & 1 = 1
        float s = 0.f;
        #pragma unroll
        for (int u = -1; u <= 1; ++u) {
            #pragma unroll
            for (int v = -1; v <= 1; ++v) {
                int py = cy + u, px = cx + v;
                if (py >= 0 && py < NKG && px >= 0 && px < NKG) {
                    int e = (1 - u) * 3 + (1 - v);
                    s += ld_ag(&P9[(((size_t)(b * NK + py * NKG + px)) * 9 + e) * PSTR + t]);
                }
            }
        }
        Sc9[((size_t)(b * NK + k0)) * PSTR + t] = s;   // plain store; dispatch boundary syncs
    }
}

// --- final E-step + dense [B,N,K] output write (zeros included), NT float4 rows ---
__global__ __launch_bounds__(256) void k_w(const float* __restrict__ feat,
                                           const float* __restrict__ Sc9,
                                           float* __restrict__ out) {
    __shared__ float pT[9 * LDST];
    __shared__ float sS[9 * PSTR];
    __shared__ float rrL[9], mtL[9];

    int blk = blockIdx.x;
    int b = blk >> 8, k0 = blk & 255;
    int cy = k0 >> 4, cx = k0 & 15;
    int t = threadIdx.x;
    int ly = t >> 4, lx = t & 15;
    int n = (cy * CELLSZ + ly) * WIMG + cx * CELLSZ + lx;

    if (t < 189) {
        int j = t / 21, c = t % 21;
        int ky = cy + j / 3 - 1, kx = cx + j % 3 - 1;
        if (ky >= 0 && ky < NKG && kx >= 0 && kx < NKG)
            sS[j * PSTR + c] = Sc9[((size_t)(b * NK + ky * NKG + kx)) * PSTR + c];
    }
    float f[NC];
    load_feat(feat, b, n, f);
    __syncthreads();
    calc_rrmt(sS, rrL, mtL, cy, cx, t);
    __syncthreads();

    float p[9];
    e_step_l(f, cy, cx, sS, rrL, mtL, p);
    #pragma unroll
    for (int j = 0; j < 9; ++j) pT[j * LDST + t] = p[j];
    __syncthreads();

    // Each wave writes full 256-float K-rows for 64 pixels: lane covers k = 4*ln..4*ln+3.
    int wv = t >> 6, ln = t & 63;
    int j4[4];
    #pragma unroll
    for (int q2 = 0; q2 < 4; ++q2) {
        int k = 4 * ln + q2;
        int ky = k >> 4, kx = k & 15;
        int dy = ky - cy, dx = kx - cx;
        j4[q2] = (dy >= -1 && dy <= 1 && dx >= -1 && dx <= 1) ? (dy + 1) * 3 + (dx + 1) : -1;
    }
    for (int i = 0; i < 64; ++i) {
        int pix = wv * 64 + i;
        int py = pix >> 4, px = pix & 15;
        int np = (cy * CELLSZ + py) * WIMG + cx * CELLSZ + px;
        floatx4 o;
        o.x = (j4[0] >= 0) ? pT[j4[0] * LDST + pix] : 0.0f;
        o.y = (j4[1] >= 0) ? pT[j4[1] * LDST + pix] : 0.0f;
        o.z = (j4[2] >= 0) ? pT[j4[2] * LDST + pix] : 0.0f;
        o.w = (j4[3] >= 0) ? pT[j4[3] * LDST + pix] : 0.0f;
        size_t rowoff = ((size_t)(b * NPIX + np)) * (size_t)NK;
        __builtin_nontemporal_store(o, (floatx4*)(out + rowoff + 4 * ln));
    }
}

// ---------------- fallback path (proven round-1 kernels, 21-stride layout) ----------------
__device__ __forceinline__ void e_step_fb(const float* f, int b, int cy, int cx,
                                          const float* __restrict__ Sprev, float p[9]) {
    float a[9];
    float amax = -1e30f;
    #pragma unroll
    for (int dy = -1; dy <= 1; ++dy) {
        #pragma unroll
        for (int dx = -1; dx <= 1; ++dx) {
            int j = (dy + 1) * 3 + (dx + 1);
            int ky = cy + dy, kx = cx + dx;
            if (ky >= 0 && ky < NKG && kx >= 0 && kx < NKG) {
                const float* sp = Sprev + ((size_t)(b * NK + ky * NKG + kx)) * NCS;
                float dots = 0.f, ssq = 0.f;
                #pragma unroll
                for (int c = 0; c < NC; ++c) {
                    float sv = sp[c];
                    dots = fmaf(f[c], sv, dots);
                    ssq  = fmaf(sv, sv, ssq);
                }
                float col = fmaxf(sp[NC], 1e-12f);
                float rr = 1.0f / col;
                a[j] = 2.0f * rr * dots - (rr * rr) * ssq;
                amax = fmaxf(amax, a[j]);
            } else {
                a[j] = -1e30f;
            }
        }
    }
    float esum = 0.f;
    #pragma unroll
    for (int j = 0; j < 9; ++j) {
        float e = (a[j] > -1e29f) ? __expf(a[j] - amax) : 0.0f;
        p[j] = e;
        esum += e;
    }
    float inv = 1.0f / esum;
    #pragma unroll
    for (int j = 0; j < 9; ++j) p[j] *= inv;
}

__global__ __launch_bounds__(256, 4) void k_init(const float* __restrict__ feat,
                                                 float* __restrict__ S0,
                                                 float* __restrict__ S1) {
    __shared__ float fT[NC * LDST];
    int blk = blockIdx.x;
    int b = blk >> 8, k0 = blk & 255;
    int cy = k0 >> 4, cx = k0 & 15;
    int t = threadIdx.x;
    int ly = t >> 4, lx = t & 15;
    int n = (cy * CELLSZ + ly) * WIMG + cx * CELLSZ + lx;
    float f[NC];
    load_feat(feat, b, n, f);
    #pragma unroll
    for (int c = 0; c < NC; ++c) fT[c * LDST + t] = f[c];
    __syncthreads();
    if (t < NCS) {
        float s;
        if (t == NC) {
            s = 256.0f;
        } else {
            s = 0.f;
            const float4* row = (const float4*)&fT[t * LDST];
            #pragma unroll 4
            for (int i = 0; i < 64; ++i) { float4 v = row[i]; s += v.x + v.y + v.z + v.w; }
        }
        size_t off = ((size_t)(b * NK + k0)) * NCS + t;
        S0[off] = s;
        S1[off] = 0.0f;
    }
}

__global__ __launch_bounds__(256, 4) void k_em(const float* __restrict__ feat,
                                               const float* __restrict__ Sprev,
                                               float* __restrict__ Snext,
                                               float* __restrict__ Szero) {
    __shared__ float fT[NCS * LDST];
    __shared__ float pT[9 * LDST];
    __shared__ float part[21 * 8 * 9];
    int blk = blockIdx.x;
    int b = blk >> 8, k0 = blk & 255;
    int cy = k0 >> 4, cx = k0 & 15;
    int t = threadIdx.x;
    int ly = t >> 4, lx = t & 15;
    int n = (cy * CELLSZ + ly) * WIMG + cx * CELLSZ + lx;
    float f[NC];
    load_feat(feat, b, n, f);
    #pragma unroll
    for (int c = 0; c < NC; ++c) fT[c * LDST + t] = f[c];
    fT[NC * LDST + t] = 1.0f;
    float p[9];
    e_step_fb(f, b, cy, cx, Sprev, p);
    #pragma unroll
    for (int j = 0; j < 9; ++j) pT[j * LDST + t] = p[j];
    __syncthreads();
    if (t < 168) {
        int tile = t >> 3, kid = t & 7;
        int j0 = (tile / 7) * 3, c0 = (tile % 7) * 3;
        float acc[3][3] = {};
        #pragma unroll
        for (int ch = 0; ch < 8; ++ch) {
            int nb = kid * 32 + (((ch + kid) & 7) << 2);
            float4 pv[3], fv[3];
            #pragma unroll
            for (int jj = 0; jj < 3; ++jj) pv[jj] = *(const float4*)&pT[(j0 + jj) * LDST + nb];
            #pragma unroll
            for (int cc = 0; cc < 3; ++cc) fv[cc] = *(const float4*)&fT[(c0 + cc) * LDST + nb];
            #pragma unroll
            for (int jj = 0; jj < 3; ++jj)
                #pragma unroll
                for (int cc = 0; cc < 3; ++cc)
                    acc[jj][cc] += dot4f(pv[jj], fv[cc]);
        }
        #pragma unroll
        for (int jj = 0; jj < 3; ++jj)
            #pragma unroll
            for (int cc = 0; cc < 3; ++cc)
                part[tile * 72 + kid * 9 + jj * 3 + cc] = acc[jj][cc];
    }
    __syncthreads();
    if (t < 189) {
        int j = t / 21, c = t % 21;
        int tile = (j / 3) * 7 + (c / 3);
        int elem = (j % 3) * 3 + (c % 3);
        float s = 0.f;
        #pragma unroll
        for (int kid = 0; kid < 8; ++kid) s += part[tile * 72 + kid * 9 + elem];
        int ky = cy + (j / 3) - 1, kx = cx + (j % 3) - 1;
        if (ky >= 0 && ky < NKG && kx >= 0 && kx < NKG)
            atomicAdd(&Snext[((size_t)(b * NK + ky * NKG + kx)) * NCS + c], s);
    }
    if (t < NCS) Szero[((size_t)(b * NK + k0)) * NCS + t] = 0.0f;
}

__global__ __launch_bounds__(256, 4) void k_final(const float* __restrict__ feat,
                                                  const float* __restrict__ Sprev,
                                                  float* __restrict__ out) {
    __shared__ float pT[9 * LDST];
    int blk = blockIdx.x;
    int b = blk >> 8, k0 = blk & 255;
    int cy = k0 >> 4, cx = k0 & 15;
    int t = threadIdx.x;
    int ly = t >> 4, lx = t & 15;
    int n = (cy * CELLSZ + ly) * WIMG + cx * CELLSZ + lx;
    float f[NC];
    load_feat(feat, b, n, f);
    float p[9];
    e_step_fb(f, b, cy, cx, Sprev, p);
    #pragma unroll
    for (int j = 0; j < 9; ++j) pT[j * LDST + t] = p[j];
    __syncthreads();
    int wv = t >> 6, ln = t & 63;
    int j4[4];
    #pragma unroll
    for (int q = 0; q < 4; ++q) {
        int k = 4 * ln + q;
        int ky = k >> 4, kx = k & 15;
        int dy = ky - cy, dx = kx - cx;
        j4[q] = (dy >= -1 && dy <= 1 && dx >= -1 && dx <= 1) ? (dy + 1) * 3 + (dx + 1) : -1;
    }
    for (int i = 0; i < 64; ++i) {
        int pix = wv * 64 + i;
        int py = pix >> 4, px = pix & 15;
        int np = (cy * CELLSZ + py) * WIMG + cx * CELLSZ + px;
        float4 o;
        o.x = (j4[0] >= 0) ? pT[j4[0] * LDST + pix] : 0.0f;
        o.y = (j4[1] >= 0) ? pT[j4[1] * LDST + pix] : 0.0f;
        o.z = (j4[2] >= 0) ? pT[j4[2] * LDST + pix] : 0.0f;
        o.w = (j4[3] >= 0) ? pT[j4[3] * LDST + pix] : 0.0f;
        size_t rowoff = ((size_t)(b * NPIX + np)) * (size_t)NK;
        *(float4*)(out + rowoff + 4 * ln) = o;
    }
}

extern "C" void kernel_launch(void* const* d_in, const int* in_sizes, int n_in,
                              void* d_out, int out_size, void* d_ws, size_t ws_size,
                              hipStream_t stream) {
    (void)in_sizes; (void)n_in; (void)out_size;
    const float* feat = (const float*)d_in[0];
    float* out = (float*)d_out;

    // ws: int done[1024] @0; Sc0, Sc9 float[B][K][PSTR]; Pp0, Pp1 float[B][K][9][PSTR].
    int* done = (int*)d_ws;
    float* Sc0 = (float*)((char*)d_ws + 4096);
    const size_t SCF = (size_t)NBATCH * NK * PSTR;        // 24576 floats
    float* Sc9 = Sc0 + SCF;
    float* Pp0 = Sc9 + SCF;
    const size_t PPF = (size_t)NBATCH * NK * 9 * PSTR;    // 221184 floats
    float* Pp1 = Pp0 + PPF;
    const size_t zneed = 4096 + (2 * SCF + 2 * PPF) * sizeof(float);

    dim3 grid(NBATCH * NK), block(256);
    if (ws_size >= zneed) {
        (void)hipMemsetAsync(d_ws, 0, 4096, stream);   // only done[] needs zeroing
        void* args[] = { (void*)&feat, (void*)&done, (void*)&Sc0, (void*)&Sc9,
                         (void*)&Pp0, (void*)&Pp1, (void*)&out };
        hipError_t err = hipLaunchCooperativeKernel((const void*)k_em9, grid, block, args, 0, stream);
        if (err == hipSuccess) {
            k_w<<<grid, block, 0, stream>>>(feat, Sc9, out);
            return;
        }
    }

    // Fallback: serial 11-kernel chain (round-1 proven path).
    const size_t SB = (size_t)NBATCH * NK * NCS;
    float* s0 = (float*)d_ws;
    float* s1 = (float*)d_ws + SB;
    float* s2 = (float*)d_ws + 2 * SB;
    float* bufs[3] = { s0, s1, s2 };
    k_init<<<grid, block, 0, stream>>>(feat, bufs[0], bufs[1]);
    for (int i = 1; i <= 9; ++i)
        k_em<<<grid, block, 0, stream>>>(feat, bufs[(i - 1) % 3], bufs[i % 3], bufs[(i + 1) % 3]);
    k_final<<<grid, block, 0, stream>>>(feat, bufs[0], out);
}